// Round 20
// baseline (534.379 us; speedup 1.0000x reference)
//
#include <hip/hip_runtime.h>
#include <hip/hip_cooperative_groups.h>
#include <math.h>

namespace cg = cooperative_groups;

#define BATCH  4
#define SEQL   4096
#define DMODEL 1024
#define NSTATE 64
#define LN_EPS 1e-5f
#define NCH    16
#define TCH    256         // SEQL / NCH
#define TB     16          // time rows per iteration (scan)
#define TSUB   8           // t-rows per corr unit

typedef unsigned short u16;
typedef unsigned int   u32;
typedef float f32x2 __attribute__((ext_vector_type(2)));

__device__ __forceinline__ f32x2 fma2(f32x2 a, f32x2 b, f32x2 c) {
#if __has_builtin(__builtin_elementwise_fma)
    return __builtin_elementwise_fma(a, b, c);
#else
    f32x2 d; d.x = fmaf(a.x, b.x, c.x); d.y = fmaf(a.y, b.y, c.y); return d;
#endif
}

__device__ __forceinline__ u16 f2bf(float x) {
    u32 b = __float_as_uint(x);
    b += 0x7FFF + ((b >> 16) & 1);       // round-to-nearest-even
    return (u16)(b >> 16);
}
__device__ __forceinline__ float bf2f(u16 h) {
    return __uint_as_float(((u32)h) << 16);
}
__device__ __forceinline__ f32x2 unpack2bf(u32 p) {
    f32x2 v; v.x = bf2f((u16)p); v.y = bf2f((u16)(p >> 16)); return v;
}

// ===========================================================================
// Fused cooperative kernel: phase1 scan -> sync -> phase2 pass2w+state ->
// sync -> phase3 corr+LN.  Grid = 1024 blocks (4/CU, co-resident).
// ===========================================================================
template <bool ZBF16>
__global__ __launch_bounds__(256) void k_fused(const float* __restrict__ u,
                                               const float* __restrict__ A_log,
                                               const float* __restrict__ C,
                                               const float* __restrict__ Dvec,
                                               const float* __restrict__ delta,
                                               const float* __restrict__ fal,
                                               const float* __restrict__ rw,
                                               const float* __restrict__ Bm,
                                               const float* __restrict__ gamma,
                                               const float* __restrict__ beta,
                                               u16* __restrict__ f,
                                               void* __restrict__ zbuf,
                                               float* __restrict__ y,
                                               float* __restrict__ st) {
    __shared__ float r_lds[NSTATE];
    __shared__ float part[2][4][TB][64];             // 32 KB, double-buffered
    __shared__ float pst_lds[NSTATE];
    __shared__ float redc[4 * TSUB * 2];
    __shared__ float red8[8];

    const int tid = threadIdx.x;
    const int bid = blockIdx.x;

    // ------------------------- phase 1: local scan -------------------------
    {
        const int w = tid >> 6, l = tid & 63;
        const int b   = bid / (16 * NCH);
        const int rem = bid % (16 * NCH);
        const int dt  = rem / NCH;
        const int j   = rem % NCH;
        const int n0  = w << 4;
        const int d   = (dt << 6) | l;

        if (tid < NSTATE) r_lds[tid] = expf(delta[0] * -expf(A_log[tid]));
        __syncthreads();

        const float fad = fal[d];
        f32x2 r2[8], c2[8], s2[8];
#pragma unroll
        for (int p = 0; p < 8; ++p) {
            r2[p] = *(const f32x2*)&r_lds[n0 + 2 * p];
            s2[p] = (f32x2)(0.f, 0.f);
        }
#pragma unroll
        for (int p = 0; p < 8; ++p) {
            c2[p].x = fad * C[(size_t)d * NSTATE + n0 + 2*p];
            c2[p].y = fad * C[(size_t)d * NSTATE + n0 + 2*p + 1];
        }

        const float Ddf = Dvec[d] * fad;
        const float rwd = rw[d];
        const float* ub = u + ((size_t)b * SEQL + (size_t)j * TCH) * DMODEL + d;
        const size_t zoff = ((size_t)b * SEQL + (size_t)j * TCH) * DMODEL + d;
        u16*   zb16 = (u16*)zbuf + zoff;
        float* zb32 = (float*)zbuf + zoff;

        for (int tb = 0; tb < TCH / TB; ++tb) {
            const int pb = tb & 1;
            float ur[TB];
            f32x2 zr2[TB];
#pragma unroll
            for (int t = 0; t < TB; ++t) {
                ur[t] = ub[(size_t)(tb * TB + t) * DMODEL];
                zr2[t] = (f32x2)(0.f, 0.f);
            }
#pragma unroll
            for (int q = 0; q < 4; ++q) {
                f32x2 sa = s2[2*q], sb2 = s2[2*q+1];
                const f32x2 ra = r2[2*q], rb = r2[2*q+1];
                const f32x2 ca = c2[2*q], cb = c2[2*q+1];
#pragma unroll
                for (int t = 0; t < TB; ++t) {
                    f32x2 u2; u2.x = ur[t]; u2.y = ur[t];
                    sa  = fma2(ra, sa,  u2);
                    sb2 = fma2(rb, sb2, u2);
                    zr2[t] = fma2(ca, sa,  zr2[t]);
                    zr2[t] = fma2(cb, sb2, zr2[t]);
                }
                s2[2*q] = sa; s2[2*q+1] = sb2;
            }
#pragma unroll
            for (int t = 0; t < TB; ++t) {
                float v = zr2[t].x + zr2[t].y;
                if (w == 0) v = fmaf(Ddf, ur[t], v);
                part[pb][w][t][l] = v;
            }
            __syncthreads();
#pragma unroll
            for (int k = 0; k < 4; ++k) {
                const int t = (w << 2) | k;
                float v = (part[pb][0][t][l] + part[pb][1][t][l]) +
                          (part[pb][2][t][l] + part[pb][3][t][l]);
                if (j == 0 && tb == 0 && t == 0) v += rwd;
                if (ZBF16) zb16[(size_t)(tb * TB + t) * DMODEL] = f2bf(v);
                else       zb32[(size_t)(tb * TB + t) * DMODEL] = v;
            }
        }
        u16* fb = f + (((size_t)b * NCH + j) * NSTATE + n0) * DMODEL + d;
#pragma unroll
        for (int p = 0; p < 8; ++p) {
            fb[(size_t)(2*p)     * DMODEL] = f2bf(s2[p].x);
            fb[(size_t)(2*p + 1) * DMODEL] = f2bf(s2[p].y);
        }
    }

    __threadfence();
    cg::this_grid().sync();

    // --------------- phase 2: boundary scan f->W (+ final state) -----------
    {
        const int gt = bid * 256 + tid;              // exactly B*N*D threads
        const int d = gt & (DMODEL - 1);
        const int n = (gt >> 10) & (NSTATE - 1);
        const int b = gt >> 16;
        const float A  = -expf(A_log[n]);
        const float rT = expf((float)TCH * delta[0] * A);
        const float fc = fal[d] * C[(size_t)d * NSTATE + n];
        float I = 0.f;
        u16* p = f + ((size_t)b * NCH * NSTATE + n) * DMODEL + d;
        const size_t stride = (size_t)NSTATE * DMODEL;
#pragma unroll
        for (int j = 0; j < NCH; ++j) {
            float tmp = bf2f(p[(size_t)j * stride]);
            p[(size_t)j * stride] = f2bf(fc * I);
            I = fmaf(rT, I, tmp);
        }
    }
    if (bid < BATCH * NSTATE) {
        const int n = bid & 63;
        const int b = bid >> 6;
        const float* ul = u + ((size_t)b * SEQL + (SEQL - 1)) * DMODEL;
        const float* Bn = Bm + (size_t)n * DMODEL;
        float dot = 0.f, dsum = 0.f;
        for (int dd = tid; dd < DMODEL; dd += 256) {
            dot = fmaf(Bn[dd], ul[dd], dot);
            dsum += delta[dd];
        }
#pragma unroll
        for (int off = 32; off > 0; off >>= 1) {
            dot  += __shfl_down(dot,  off, 64);
            dsum += __shfl_down(dsum, off, 64);
        }
        const int wave = tid >> 6, lane = tid & 63;
        if (lane == 0) { red8[wave] = dot; red8[4 + wave] = dsum; }
        __syncthreads();
        if (tid == 0) {
            dot  = red8[0] + red8[1] + red8[2] + red8[3];
            dsum = red8[4] + red8[5] + red8[6] + red8[7];
            const float dmean = dsum * (1.f / DMODEL);
            const float A = -expf(A_log[n]);
            const float Abar = expf(dmean * A);
            const float Asafe = A + (A >= 0.f ? 1e-8f : -1e-8f);
            st[bid] = ((Abar - 1.f) / Asafe) * dot;
        }
    }

    __threadfence();
    cg::this_grid().sync();

    // ------------------- phase 3: corr + LayerNorm (2 units) ---------------
    {
        // XCD-pinned mapping: slab s (= b*NCH+j, 64 total) -> XCD s%8;
        // blocks on XCD x (bid%8==x) serve slabs s%8==x -> W slab stays in
        // that XCD's L2 (128 KB x 8 slabs = 1 MB).
        const int x = bid & 7;
        const int m = bid >> 3;                      // 0..127
        const int k = m >> 4;                        // 0..7
        const int s = x + (k << 3);                  // slab, s%8 == x
        const int b = s >> 4;
        const int j = s & (NCH - 1);
        const int ui0 = (m & 15) << 1;

        const int d0 = tid << 2;
        const int wave = tid >> 6, lane = tid & 63;
        const float4 g  = *(const float4*)&gamma[d0];
        const float4 bb = *(const float4*)&beta[d0];

#pragma unroll 1
        for (int e = 0; e < 2; ++e) {
            const int row = j * (TCH / TSUB) + ui0 + e;   // row within b
            const int tbase = row * TSUB;
            const int tloc0 = tbase & (TCH - 1);

            __syncthreads();
            if (tid < NSTATE) {
                const float A = -expf(A_log[tid]);
                const float d0v = delta[0];
                r_lds[tid]   = expf(d0v * A);
                pst_lds[tid] = expf((float)(tloc0 + 1) * d0v * A);
            }
            __syncthreads();

            f32x2 acc01[TSUB], acc23[TSUB];
#pragma unroll
            for (int t = 0; t < TSUB; ++t) {
                acc01[t] = (f32x2)(0.f, 0.f);
                acc23[t] = (f32x2)(0.f, 0.f);
            }

            if (j > 0) {
                const u16* Wb = f + (((size_t)b * NCH + j) * NSTATE) * DMODEL + d0;
#pragma unroll 2
                for (int n = 0; n < NSTATE; ++n) {
                    const uint2 wv = *(const uint2*)(Wb + (size_t)n * DMODEL);
                    const f32x2 w01 = unpack2bf(wv.x);
                    const f32x2 w23 = unpack2bf(wv.y);
                    float p = pst_lds[n];
                    const float r = r_lds[n];
#pragma unroll
                    for (int t = 0; t < TSUB; ++t) {
                        f32x2 pp; pp.x = p; pp.y = p;
                        acc01[t] = fma2(pp, w01, acc01[t]);
                        acc23[t] = fma2(pp, w23, acc23[t]);
                        p *= r;
                    }
                }
            }

            const size_t rowoff = ((size_t)b * SEQL + tbase) * DMODEL + d0;
            float sums[TSUB], sqs[TSUB];
#pragma unroll
            for (int t = 0; t < TSUB; ++t) {
                float z0, z1, z2, z3;
                if (ZBF16) {
                    const uint2 zv = *(const uint2*)((const u16*)zbuf + rowoff + (size_t)t * DMODEL);
                    const f32x2 a = unpack2bf(zv.x), b2 = unpack2bf(zv.y);
                    z0 = a.x; z1 = a.y; z2 = b2.x; z3 = b2.y;
                } else {
                    const float4 zv = *(const float4*)((const float*)zbuf + rowoff + (size_t)t * DMODEL);
                    z0 = zv.x; z1 = zv.y; z2 = zv.z; z3 = zv.w;
                }
                z0 += acc01[t].x; z1 += acc01[t].y; z2 += acc23[t].x; z3 += acc23[t].y;
                acc01[t].x = z0; acc01[t].y = z1; acc23[t].x = z2; acc23[t].y = z3;
                sums[t] = (z0 + z1) + (z2 + z3);
                sqs[t]  = (z0*z0 + z1*z1) + (z2*z2 + z3*z3);
            }
#pragma unroll
            for (int t = 0; t < TSUB; ++t) {
                float sv = sums[t], q = sqs[t];
#pragma unroll
                for (int off = 32; off > 0; off >>= 1) {
                    sv += __shfl_down(sv, off, 64);
                    q  += __shfl_down(q,  off, 64);
                }
                if (lane == 0) {
                    redc[(wave * TSUB + t) * 2]     = sv;
                    redc[(wave * TSUB + t) * 2 + 1] = q;
                }
            }
            __syncthreads();
#pragma unroll
            for (int t = 0; t < TSUB; ++t) {
                float sv = redc[t * 2]     + redc[(TSUB + t) * 2] +
                           redc[(2 * TSUB + t) * 2] + redc[(3 * TSUB + t) * 2];
                float q  = redc[t * 2 + 1] + redc[(TSUB + t) * 2 + 1] +
                           redc[(2 * TSUB + t) * 2 + 1] + redc[(3 * TSUB + t) * 2 + 1];
                const float mean = sv * (1.f / DMODEL);
                const float var  = q * (1.f / DMODEL) - mean * mean;
                const float inv  = 1.f / sqrtf(var + LN_EPS);
                float4 o;
                o.x = (acc01[t].x - mean) * inv * g.x + bb.x;
                o.y = (acc01[t].y - mean) * inv * g.y + bb.y;
                o.z = (acc23[t].x - mean) * inv * g.z + bb.z;
                o.w = (acc23[t].y - mean) * inv * g.w + bb.w;
                *(float4*)&y[rowoff + (size_t)t * DMODEL] = o;
            }
        }
    }
}

// ===========================================================================
// Fallback (non-cooperative) path: round-19 kernels, used only if the
// cooperative launch is rejected by the runtime.
// ===========================================================================
template <bool ZBF16>
__global__ __launch_bounds__(256) void k_scan(const float* __restrict__ u,
                                              const float* __restrict__ A_log,
                                              const float* __restrict__ C,
                                              const float* __restrict__ Dvec,
                                              const float* __restrict__ delta,
                                              const float* __restrict__ fal,
                                              const float* __restrict__ rw,
                                              const float* __restrict__ Bm,
                                              u16* __restrict__ f,
                                              void* __restrict__ zout,
                                              float* __restrict__ st,
                                              int nb) {
    if (blockIdx.x >= nb) {
        const int sb = blockIdx.x - nb;
        const int n = sb & 63;
        const int b = sb >> 6;
        const int tid = threadIdx.x;
        const float* ul = u + ((size_t)b * SEQL + (SEQL - 1)) * DMODEL;
        const float* Bn = Bm + (size_t)n * DMODEL;
        float dot = 0.f, dsum = 0.f;
        for (int dd = tid; dd < DMODEL; dd += 256) {
            dot = fmaf(Bn[dd], ul[dd], dot);
            dsum += delta[dd];
        }
#pragma unroll
        for (int off = 32; off > 0; off >>= 1) {
            dot  += __shfl_down(dot,  off, 64);
            dsum += __shfl_down(dsum, off, 64);
        }
        __shared__ float red[8];
        const int wave = tid >> 6, lane = tid & 63;
        if (lane == 0) { red[wave] = dot; red[4 + wave] = dsum; }
        __syncthreads();
        if (tid == 0) {
            dot  = red[0] + red[1] + red[2] + red[3];
            dsum = red[4] + red[5] + red[6] + red[7];
            const float dmean = dsum * (1.f / DMODEL);
            const float A = -expf(A_log[n]);
            const float Abar = expf(dmean * A);
            const float Asafe = A + (A >= 0.f ? 1e-8f : -1e-8f);
            st[sb] = ((Abar - 1.f) / Asafe) * dot;
        }
        return;
    }
    __shared__ float r_lds[NSTATE];
    __shared__ float part[2][4][TB][64];
    const int tid = threadIdx.x;
    const int w = tid >> 6, l = tid & 63;
    const int b   = blockIdx.x / (16 * NCH);
    const int rem = blockIdx.x % (16 * NCH);
    const int dt  = rem / NCH;
    const int j   = rem % NCH;
    const int n0  = w << 4;
    const int d   = (dt << 6) | l;

    if (tid < NSTATE) r_lds[tid] = expf(delta[0] * -expf(A_log[tid]));
    __syncthreads();

    const float fad = fal[d];
    f32x2 r2[8], c2[8], s2[8];
#pragma unroll
    for (int p = 0; p < 8; ++p) {
        r2[p] = *(const f32x2*)&r_lds[n0 + 2 * p];
        s2[p] = (f32x2)(0.f, 0.f);
    }
#pragma unroll
    for (int p = 0; p < 8; ++p) {
        c2[p].x = fad * C[(size_t)d * NSTATE + n0 + 2*p];
        c2[p].y = fad * C[(size_t)d * NSTATE + n0 + 2*p + 1];
    }
    const float Ddf = Dvec[d] * fad;
    const float rwd = rw[d];
    const float* ub = u + ((size_t)b * SEQL + (size_t)j * TCH) * DMODEL + d;
    const size_t zoff = ((size_t)b * SEQL + (size_t)j * TCH) * DMODEL + d;
    u16*   zb16 = (u16*)zout + zoff;
    float* zb32 = (float*)zout + zoff;

    for (int tb = 0; tb < TCH / TB; ++tb) {
        const int pb = tb & 1;
        float ur[TB];
        f32x2 zr2[TB];
#pragma unroll
        for (int t = 0; t < TB; ++t) {
            ur[t] = ub[(size_t)(tb * TB + t) * DMODEL];
            zr2[t] = (f32x2)(0.f, 0.f);
        }
#pragma unroll
        for (int q = 0; q < 4; ++q) {
            f32x2 sa = s2[2*q], sb2 = s2[2*q+1];
            const f32x2 ra = r2[2*q], rb = r2[2*q+1];
            const f32x2 ca = c2[2*q], cb = c2[2*q+1];
#pragma unroll
            for (int t = 0; t < TB; ++t) {
                f32x2 u2; u2.x = ur[t]; u2.y = ur[t];
                sa  = fma2(ra, sa,  u2);
                sb2 = fma2(rb, sb2, u2);
                zr2[t] = fma2(ca, sa,  zr2[t]);
                zr2[t] = fma2(cb, sb2, zr2[t]);
            }
            s2[2*q] = sa; s2[2*q+1] = sb2;
        }
#pragma unroll
        for (int t = 0; t < TB; ++t) {
            float v = zr2[t].x + zr2[t].y;
            if (w == 0) v = fmaf(Ddf, ur[t], v);
            part[pb][w][t][l] = v;
        }
        __syncthreads();
#pragma unroll
        for (int k = 0; k < 4; ++k) {
            const int t = (w << 2) | k;
            float v = (part[pb][0][t][l] + part[pb][1][t][l]) +
                      (part[pb][2][t][l] + part[pb][3][t][l]);
            if (j == 0 && tb == 0 && t == 0) v += rwd;
            if (ZBF16) zb16[(size_t)(tb * TB + t) * DMODEL] = f2bf(v);
            else       zb32[(size_t)(tb * TB + t) * DMODEL] = v;
        }
    }
    u16* fb = f + (((size_t)b * NCH + j) * NSTATE + n0) * DMODEL + d;
#pragma unroll
    for (int p = 0; p < 8; ++p) {
        fb[(size_t)(2*p)     * DMODEL] = f2bf(s2[p].x);
        fb[(size_t)(2*p + 1) * DMODEL] = f2bf(s2[p].y);
    }
}

__global__ __launch_bounds__(256) void k_pass2w(const float* __restrict__ A_log,
                                                const float* __restrict__ delta,
                                                const float* __restrict__ C,
                                                const float* __restrict__ fal,
                                                u16* __restrict__ f) {
    const int tid = blockIdx.x * 256 + threadIdx.x;
    const int d = tid & (DMODEL - 1);
    const int n = (tid >> 10) & (NSTATE - 1);
    const int b = tid >> 16;
    const float A  = -expf(A_log[n]);
    const float rT = expf((float)TCH * delta[0] * A);
    const float fc = fal[d] * C[(size_t)d * NSTATE + n];
    float I = 0.f;
    u16* p = f + ((size_t)b * NCH * NSTATE + n) * DMODEL + d;
    const size_t stride = (size_t)NSTATE * DMODEL;
    for (int j = 0; j < NCH; ++j) {
        float tmp = bf2f(p[(size_t)j * stride]);
        p[(size_t)j * stride] = f2bf(fc * I);
        I = fmaf(rT, I, tmp);
    }
}

template <bool ZBF16>
__global__ __launch_bounds__(256) void k_corr_ln(const void* __restrict__ zin,
                                                 const u16* __restrict__ W,
                                                 const float* __restrict__ A_log,
                                                 const float* __restrict__ delta,
                                                 const float* __restrict__ gamma,
                                                 const float* __restrict__ beta,
                                                 float* __restrict__ y) {
    const int lb  = (blockIdx.x & 7) * 256 + (blockIdx.x >> 3);
    const int b   = lb >> 9;
    const int row = lb & 511;
    const int tbase = row * TSUB;
    const int j     = tbase >> 8;
    const int tloc0 = tbase & (TCH - 1);

    __shared__ float r_lds[NSTATE];
    __shared__ float pst_lds[NSTATE];
    __shared__ float red[4 * TSUB * 2];

    const int tid = threadIdx.x;
    if (tid < NSTATE) {
        const float A = -expf(A_log[tid]);
        const float d0v = delta[0];
        r_lds[tid]   = expf(d0v * A);
        pst_lds[tid] = expf((float)(tloc0 + 1) * d0v * A);
    }
    __syncthreads();

    const int d0 = tid << 2;
    f32x2 acc01[TSUB], acc23[TSUB];
#pragma unroll
    for (int t = 0; t < TSUB; ++t) {
        acc01[t] = (f32x2)(0.f, 0.f);
        acc23[t] = (f32x2)(0.f, 0.f);
    }
    if (j > 0) {
        const u16* Wb = W + (((size_t)b * NCH + j) * NSTATE) * DMODEL + d0;
#pragma unroll 2
        for (int n = 0; n < NSTATE; ++n) {
            const uint2 wv = *(const uint2*)(Wb + (size_t)n * DMODEL);
            const f32x2 w01 = unpack2bf(wv.x);
            const f32x2 w23 = unpack2bf(wv.y);
            float p = pst_lds[n];
            const float r = r_lds[n];
#pragma unroll
            for (int t = 0; t < TSUB; ++t) {
                f32x2 pp; pp.x = p; pp.y = p;
                acc01[t] = fma2(pp, w01, acc01[t]);
                acc23[t] = fma2(pp, w23, acc23[t]);
                p *= r;
            }
        }
    }
    const size_t rowoff = ((size_t)b * SEQL + tbase) * DMODEL + d0;
    float sums[TSUB], sqs[TSUB];
#pragma unroll
    for (int t = 0; t < TSUB; ++t) {
        float z0, z1, z2, z3;
        if (ZBF16) {
            const uint2 zv = *(const uint2*)((const u16*)zin + rowoff + (size_t)t * DMODEL);
            const f32x2 a = unpack2bf(zv.x), bb2 = unpack2bf(zv.y);
            z0 = a.x; z1 = a.y; z2 = bb2.x; z3 = bb2.y;
        } else {
            const float4 zv = *(const float4*)((const float*)zin + rowoff + (size_t)t * DMODEL);
            z0 = zv.x; z1 = zv.y; z2 = zv.z; z3 = zv.w;
        }
        z0 += acc01[t].x; z1 += acc01[t].y; z2 += acc23[t].x; z3 += acc23[t].y;
        acc01[t].x = z0; acc01[t].y = z1; acc23[t].x = z2; acc23[t].y = z3;
        sums[t] = (z0 + z1) + (z2 + z3);
        sqs[t]  = (z0*z0 + z1*z1) + (z2*z2 + z3*z3);
    }
    const int wave = tid >> 6, lane = tid & 63;
#pragma unroll
    for (int t = 0; t < TSUB; ++t) {
        float s = sums[t], q = sqs[t];
#pragma unroll
        for (int off = 32; off > 0; off >>= 1) {
            s += __shfl_down(s, off, 64);
            q += __shfl_down(q, off, 64);
        }
        if (lane == 0) {
            red[(wave * TSUB + t) * 2]     = s;
            red[(wave * TSUB + t) * 2 + 1] = q;
        }
    }
    __syncthreads();
    const float4 g  = *(const float4*)&gamma[d0];
    const float4 bb = *(const float4*)&beta[d0];
#pragma unroll
    for (int t = 0; t < TSUB; ++t) {
        float s = red[t * 2]     + red[(TSUB + t) * 2] +
                  red[(2 * TSUB + t) * 2] + red[(3 * TSUB + t) * 2];
        float q = red[t * 2 + 1] + red[(TSUB + t) * 2 + 1] +
                  red[(2 * TSUB + t) * 2 + 1] + red[(3 * TSUB + t) * 2 + 1];
        const float mean = s * (1.f / DMODEL);
        const float var  = q * (1.f / DMODEL) - mean * mean;
        const float inv  = 1.f / sqrtf(var + LN_EPS);
        float4 o;
        o.x = (acc01[t].x - mean) * inv * g.x + bb.x;
        o.y = (acc01[t].y - mean) * inv * g.y + bb.y;
        o.z = (acc23[t].x - mean) * inv * g.z + bb.z;
        o.w = (acc23[t].y - mean) * inv * g.w + bb.w;
        *(float4*)&y[rowoff + (size_t)t * DMODEL] = o;
    }
}

extern "C" void kernel_launch(void* const* d_in, const int* in_sizes, int n_in,
                              void* d_out, int out_size, void* d_ws, size_t ws_size,
                              hipStream_t stream) {
    const float* u     = (const float*)d_in[0];
    const float* A_log = (const float*)d_in[1];
    const float* B     = (const float*)d_in[2];
    const float* C     = (const float*)d_in[3];
    const float* Dv    = (const float*)d_in[4];
    const float* delta = (const float*)d_in[5];
    const float* gamma = (const float*)d_in[6];
    const float* beta  = (const float*)d_in[7];
    const float* fal   = (const float*)d_in[8];
    const float* rw    = (const float*)d_in[9];

    float* y  = (float*)d_out;
    float* st = y + (size_t)BATCH * SEQL * DMODEL;
    u16* f    = (u16*)d_ws;

    const int nb = BATCH * 16 * NCH;                  // 1024 blocks

    const size_t f_bytes = (size_t)BATCH * NCH * NSTATE * DMODEL * sizeof(u16);
    const size_t z_bytes = (size_t)BATCH * SEQL * DMODEL * sizeof(u16);
    const bool zbf16 = (f_bytes + z_bytes) <= ws_size;
    void* zbuf = zbf16 ? (void*)((char*)d_ws + f_bytes) : (void*)y;

    // ---- try the fused cooperative path (1 launch, 2 grid syncs) ----
    void* args[] = {(void*)&u, (void*)&A_log, (void*)&C, (void*)&Dv, (void*)&delta,
                    (void*)&fal, (void*)&rw, (void*)&B, (void*)&gamma, (void*)&beta,
                    (void*)&f, (void*)&zbuf, (void*)&y, (void*)&st};
    hipError_t err = hipLaunchCooperativeKernel(
        zbf16 ? (const void*)(k_fused<true>) : (const void*)(k_fused<false>),
        dim3(nb), dim3(256), args, 0, stream);

    if (err != hipSuccess) {
        // ---- fallback: 3-kernel path (round-19 structure) ----
        if (zbf16) {
            hipLaunchKernelGGL((k_scan<true>), dim3(nb + BATCH * NSTATE), dim3(256), 0, stream,
                               u, A_log, C, Dv, delta, fal, rw, B, f, zbuf, st, nb);
        } else {
            hipLaunchKernelGGL((k_scan<false>), dim3(nb + BATCH * NSTATE), dim3(256), 0, stream,
                               u, A_log, C, Dv, delta, fal, rw, B, f, zbuf, st, nb);
        }
        hipLaunchKernelGGL(k_pass2w, dim3(BATCH * NSTATE * DMODEL / 256), dim3(256), 0, stream,
                           A_log, delta, C, fal, f);
        if (zbf16) {
            hipLaunchKernelGGL((k_corr_ln<true>), dim3(BATCH * (SEQL / TSUB)), dim3(256), 0, stream,
                               zbuf, f, A_log, delta, gamma, beta, y);
        } else {
            hipLaunchKernelGGL((k_corr_ln<false>), dim3(BATCH * (SEQL / TSUB)), dim3(256), 0, stream,
                               zbuf, f, A_log, delta, gamma, beta, y);
        }
    }
}

// Round 21
// 115.112 us; speedup vs baseline: 4.6423x; 4.6423x over previous
//
#include <hip/hip_runtime.h>
#include <math.h>

#define BATCH  4
#define SEQL   4096
#define DMODEL 1024
#define NSTATE 64
#define LN_EPS 1e-5f
#define NCH    16
#define TCH    256         // SEQL / NCH
#define TB     16          // time rows per iteration (scan)
#define TSUB   8           // t-rows per block (corr_ln)

typedef unsigned short u16;
typedef unsigned int   u32;
typedef float f32x2 __attribute__((ext_vector_type(2)));

__device__ __forceinline__ f32x2 fma2(f32x2 a, f32x2 b, f32x2 c) {
#if __has_builtin(__builtin_elementwise_fma)
    return __builtin_elementwise_fma(a, b, c);
#else
    f32x2 d; d.x = fmaf(a.x, b.x, c.x); d.y = fmaf(a.y, b.y, c.y); return d;
#endif
}

__device__ __forceinline__ u16 f2bf(float x) {
    u32 b = __float_as_uint(x);
    b += 0x7FFF + ((b >> 16) & 1);       // round-to-nearest-even
    return (u16)(b >> 16);
}
__device__ __forceinline__ float bf2f(u16 h) {
    return __uint_as_float(((u32)h) << 16);
}
__device__ __forceinline__ f32x2 unpack2bf(u32 p) {
    f32x2 v; v.x = bf2f((u16)p); v.y = bf2f((u16)(p >> 16)); return v;
}

// ---------------------------------------------------------------------------
// k_scan<ZBF16>: ZERO-init scan per (b, d-tile 64, chunk j); 4 waves, wave w
// owns n in [16w,16w+16), lane = d. Emits BOTH
//   z_local[t,d] = fal[d]*( sum_n C[d,n] s_loc[n,t,d] + D[d] u[t,d] )
//                  + reward[d]*(global t==0)
//   f[b][j][n][d] = local final state (bf16)
// fal folded into c/D. Packed pairs; part-LDS double-buffered, one barrier
// per TB tile. State-path blocks (blockIdx >= nb) fused into this launch.
// ---------------------------------------------------------------------------
template <bool ZBF16>
__global__ __launch_bounds__(256) void k_scan(const float* __restrict__ u,
                                              const float* __restrict__ A_log,
                                              const float* __restrict__ C,
                                              const float* __restrict__ Dvec,
                                              const float* __restrict__ delta,
                                              const float* __restrict__ fal,
                                              const float* __restrict__ rw,
                                              const float* __restrict__ Bm,
                                              u16* __restrict__ f,
                                              void* __restrict__ zout,
                                              float* __restrict__ st,
                                              int nb) {
    if (blockIdx.x >= nb) {
        // ------------------- final-state path -------------------
        const int sb = blockIdx.x - nb;
        const int n = sb & 63;
        const int b = sb >> 6;
        const int tid = threadIdx.x;
        const float* ul = u + ((size_t)b * SEQL + (SEQL - 1)) * DMODEL;
        const float* Bn = Bm + (size_t)n * DMODEL;
        float dot = 0.f, dsum = 0.f;
        for (int dd = tid; dd < DMODEL; dd += 256) {
            dot = fmaf(Bn[dd], ul[dd], dot);
            dsum += delta[dd];
        }
#pragma unroll
        for (int off = 32; off > 0; off >>= 1) {
            dot  += __shfl_down(dot,  off, 64);
            dsum += __shfl_down(dsum, off, 64);
        }
        __shared__ float red[8];
        const int wave = tid >> 6, lane = tid & 63;
        if (lane == 0) { red[wave] = dot; red[4 + wave] = dsum; }
        __syncthreads();
        if (tid == 0) {
            dot  = red[0] + red[1] + red[2] + red[3];
            dsum = red[4] + red[5] + red[6] + red[7];
            const float dmean = dsum * (1.f / DMODEL);
            const float A = -expf(A_log[n]);
            const float Abar = expf(dmean * A);
            const float Asafe = A + (A >= 0.f ? 1e-8f : -1e-8f);
            st[sb] = ((Abar - 1.f) / Asafe) * dot;
        }
        return;
    }
    // ------------------- scan path -------------------
    __shared__ float r_lds[NSTATE];
    __shared__ float part[2][4][TB][64];             // 32 KB, double-buffered
    const int tid = threadIdx.x;
    const int w = tid >> 6, l = tid & 63;
    const int b   = blockIdx.x / (16 * NCH);
    const int rem = blockIdx.x % (16 * NCH);
    const int dt  = rem / NCH;
    const int j   = rem % NCH;
    const int n0  = w << 4;
    const int d   = (dt << 6) | l;

    if (tid < NSTATE) r_lds[tid] = expf(delta[0] * -expf(A_log[tid]));
    __syncthreads();

    const float fad = fal[d];
    f32x2 r2[8], c2[8], s2[8];
#pragma unroll
    for (int p = 0; p < 8; ++p) {
        r2[p] = *(const f32x2*)&r_lds[n0 + 2 * p];
        s2[p] = (f32x2)(0.f, 0.f);
    }
#pragma unroll
    for (int p = 0; p < 8; ++p) {
        c2[p].x = fad * C[(size_t)d * NSTATE + n0 + 2*p];
        c2[p].y = fad * C[(size_t)d * NSTATE + n0 + 2*p + 1];
    }

    const float Ddf = Dvec[d] * fad;
    const float rwd = rw[d];
    const float* ub = u + ((size_t)b * SEQL + (size_t)j * TCH) * DMODEL + d;
    const size_t zoff = ((size_t)b * SEQL + (size_t)j * TCH) * DMODEL + d;
    u16*   zb16 = (u16*)zout + zoff;
    float* zb32 = (float*)zout + zoff;

    for (int tb = 0; tb < TCH / TB; ++tb) {
        const int pb = tb & 1;
        float ur[TB];
        f32x2 zr2[TB];
#pragma unroll
        for (int t = 0; t < TB; ++t) {
            ur[t] = ub[(size_t)(tb * TB + t) * DMODEL];
            zr2[t] = (f32x2)(0.f, 0.f);
        }
#pragma unroll
        for (int q = 0; q < 4; ++q) {
            f32x2 sa = s2[2*q], sb2 = s2[2*q+1];
            const f32x2 ra = r2[2*q], rb = r2[2*q+1];
            const f32x2 ca = c2[2*q], cb = c2[2*q+1];
#pragma unroll
            for (int t = 0; t < TB; ++t) {
                f32x2 u2; u2.x = ur[t]; u2.y = ur[t];
                sa  = fma2(ra, sa,  u2);
                sb2 = fma2(rb, sb2, u2);
                zr2[t] = fma2(ca, sa,  zr2[t]);
                zr2[t] = fma2(cb, sb2, zr2[t]);
            }
            s2[2*q] = sa; s2[2*q+1] = sb2;
        }
#pragma unroll
        for (int t = 0; t < TB; ++t) {
            float v = zr2[t].x + zr2[t].y;
            if (w == 0) v = fmaf(Ddf, ur[t], v);     // fal-folded D-term, once
            part[pb][w][t][l] = v;
        }
        __syncthreads();
#pragma unroll
        for (int k = 0; k < 4; ++k) {
            const int t = (w << 2) | k;
            float v = (part[pb][0][t][l] + part[pb][1][t][l]) +
                      (part[pb][2][t][l] + part[pb][3][t][l]);
            if (j == 0 && tb == 0 && t == 0) v += rwd;
            if (ZBF16) zb16[(size_t)(tb * TB + t) * DMODEL] = f2bf(v);
            else       zb32[(size_t)(tb * TB + t) * DMODEL] = v;
        }
    }
    // epilogue: write local finals (bf16)
    u16* fb = f + (((size_t)b * NCH + j) * NSTATE + n0) * DMODEL + d;
#pragma unroll
    for (int p = 0; p < 8; ++p) {
        fb[(size_t)(2*p)     * DMODEL] = f2bf(s2[p].x);
        fb[(size_t)(2*p + 1) * DMODEL] = f2bf(s2[p].y);
    }
}

// ---------------------------------------------------------------------------
// k_pass2w: boundary scan, in place. f[b][j][n][d] (local finals, bf16) ->
// W[b][j][n][d] = fal[d] * C[d,n] * I_j[n,d]  (bf16), I accumulated in f32.
// One thread per (b,n,d).
// ---------------------------------------------------------------------------
__global__ __launch_bounds__(256) void k_pass2w(const float* __restrict__ A_log,
                                                const float* __restrict__ delta,
                                                const float* __restrict__ C,
                                                const float* __restrict__ fal,
                                                u16* __restrict__ f) {
    const int tid = blockIdx.x * 256 + threadIdx.x;  // over B*N*D
    const int d = tid & (DMODEL - 1);
    const int n = (tid >> 10) & (NSTATE - 1);
    const int b = tid >> 16;
    const float A  = -expf(A_log[n]);
    const float rT = expf((float)TCH * delta[0] * A);
    const float fc = fal[d] * C[(size_t)d * NSTATE + n];  // scattered, L2-cached
    float I = 0.f;
    u16* p = f + ((size_t)b * NCH * NSTATE + n) * DMODEL + d;
    const size_t stride = (size_t)NSTATE * DMODEL;
    for (int j = 0; j < NCH; ++j) {
        float tmp = bf2f(p[(size_t)j * stride]);
        p[(size_t)j * stride] = f2bf(fc * I);
        I = fmaf(rT, I, tmp);
    }
}

// ---------------------------------------------------------------------------
// k_corr_ln<ZBF16>: block = (b, 8 t-rows) x all 1024 d; 256 threads x 4 d.
//   corr[t,d] = sum_n r_n^{tloc+t+1} * W[n,d]   (p via register recurrence)
//   z = z_local + corr;  out = LayerNorm_d(z)*gamma + beta  -> f32 y
// XCD-bijective swizzle: the 32 blocks sharing one (b,j) W-slab (128 KB)
// land on one XCD so its L2 serves the re-reads.
// ---------------------------------------------------------------------------
template <bool ZBF16>
__global__ __launch_bounds__(256) void k_corr_ln(const void* __restrict__ zin,
                                                 const u16* __restrict__ W,
                                                 const float* __restrict__ A_log,
                                                 const float* __restrict__ delta,
                                                 const float* __restrict__ gamma,
                                                 const float* __restrict__ beta,
                                                 float* __restrict__ y) {
    // bijective XCD swizzle: nwg = 2048, 8 XCDs, 256 per XCD
    const int lb  = (blockIdx.x & 7) * 256 + (blockIdx.x >> 3);
    const int b   = lb >> 9;                 // / 512
    const int row = lb & 511;
    const int tbase = row * TSUB;
    const int j     = tbase >> 8;            // / TCH
    const int tloc0 = tbase & (TCH - 1);

    __shared__ float r_lds[NSTATE];
    __shared__ float pst_lds[NSTATE];
    __shared__ float red[4 * TSUB * 2];

    const int tid = threadIdx.x;
    if (tid < NSTATE) {
        const float A = -expf(A_log[tid]);
        const float d0v = delta[0];
        r_lds[tid]   = expf(d0v * A);
        pst_lds[tid] = expf((float)(tloc0 + 1) * d0v * A);
    }
    __syncthreads();

    const int d0 = tid << 2;
    f32x2 acc01[TSUB], acc23[TSUB];
#pragma unroll
    for (int t = 0; t < TSUB; ++t) {
        acc01[t] = (f32x2)(0.f, 0.f);
        acc23[t] = (f32x2)(0.f, 0.f);
    }

    if (j > 0) {
        const u16* Wb = W + (((size_t)b * NCH + j) * NSTATE) * DMODEL + d0;
#pragma unroll 2
        for (int n = 0; n < NSTATE; ++n) {
            const uint2 wv = *(const uint2*)(Wb + (size_t)n * DMODEL);
            const f32x2 w01 = unpack2bf(wv.x);
            const f32x2 w23 = unpack2bf(wv.y);
            float p = pst_lds[n];
            const float r = r_lds[n];
#pragma unroll
            for (int t = 0; t < TSUB; ++t) {
                f32x2 pp; pp.x = p; pp.y = p;
                acc01[t] = fma2(pp, w01, acc01[t]);
                acc23[t] = fma2(pp, w23, acc23[t]);
                p *= r;
            }
        }
    }

    // add z_local, LN stats
    const size_t rowoff = ((size_t)b * SEQL + tbase) * DMODEL + d0;
    float sums[TSUB], sqs[TSUB];
#pragma unroll
    for (int t = 0; t < TSUB; ++t) {
        float z0, z1, z2, z3;
        if (ZBF16) {
            const uint2 zv = *(const uint2*)((const u16*)zin + rowoff + (size_t)t * DMODEL);
            const f32x2 a = unpack2bf(zv.x), bb2 = unpack2bf(zv.y);
            z0 = a.x; z1 = a.y; z2 = bb2.x; z3 = bb2.y;
        } else {
            const float4 zv = *(const float4*)((const float*)zin + rowoff + (size_t)t * DMODEL);
            z0 = zv.x; z1 = zv.y; z2 = zv.z; z3 = zv.w;
        }
        z0 += acc01[t].x; z1 += acc01[t].y; z2 += acc23[t].x; z3 += acc23[t].y;
        acc01[t].x = z0; acc01[t].y = z1; acc23[t].x = z2; acc23[t].y = z3;
        sums[t] = (z0 + z1) + (z2 + z3);
        sqs[t]  = (z0*z0 + z1*z1) + (z2*z2 + z3*z3);
    }
    const int wave = tid >> 6, lane = tid & 63;
#pragma unroll
    for (int t = 0; t < TSUB; ++t) {
        float s = sums[t], q = sqs[t];
#pragma unroll
        for (int off = 32; off > 0; off >>= 1) {
            s += __shfl_down(s, off, 64);
            q += __shfl_down(q, off, 64);
        }
        if (lane == 0) {
            red[(wave * TSUB + t) * 2]     = s;
            red[(wave * TSUB + t) * 2 + 1] = q;
        }
    }
    __syncthreads();
    const float4 g  = *(const float4*)&gamma[d0];
    const float4 bb = *(const float4*)&beta[d0];
#pragma unroll
    for (int t = 0; t < TSUB; ++t) {
        float s = red[t * 2]     + red[(TSUB + t) * 2] +
                  red[(2 * TSUB + t) * 2] + red[(3 * TSUB + t) * 2];
        float q = red[t * 2 + 1] + red[(TSUB + t) * 2 + 1] +
                  red[(2 * TSUB + t) * 2 + 1] + red[(3 * TSUB + t) * 2 + 1];
        const float mean = s * (1.f / DMODEL);
        const float var  = q * (1.f / DMODEL) - mean * mean;
        const float inv  = 1.f / sqrtf(var + LN_EPS);
        float4 o;
        o.x = (acc01[t].x - mean) * inv * g.x + bb.x;
        o.y = (acc01[t].y - mean) * inv * g.y + bb.y;
        o.z = (acc23[t].x - mean) * inv * g.z + bb.z;
        o.w = (acc23[t].y - mean) * inv * g.w + bb.w;
        *(float4*)&y[rowoff + (size_t)t * DMODEL] = o;
    }
}

extern "C" void kernel_launch(void* const* d_in, const int* in_sizes, int n_in,
                              void* d_out, int out_size, void* d_ws, size_t ws_size,
                              hipStream_t stream) {
    const float* u     = (const float*)d_in[0];
    const float* A_log = (const float*)d_in[1];
    const float* B     = (const float*)d_in[2];
    const float* C     = (const float*)d_in[3];
    const float* Dv    = (const float*)d_in[4];
    const float* delta = (const float*)d_in[5];
    const float* gamma = (const float*)d_in[6];
    const float* beta  = (const float*)d_in[7];
    const float* fal   = (const float*)d_in[8];
    const float* rw    = (const float*)d_in[9];

    float* y  = (float*)d_out;
    float* st = y + (size_t)BATCH * SEQL * DMODEL;
    u16* f    = (u16*)d_ws;

    const int nb = BATCH * 16 * NCH;                  // 1024 scan blocks

    const size_t f_bytes = (size_t)BATCH * NCH * NSTATE * DMODEL * sizeof(u16);
    const size_t z_bytes = (size_t)BATCH * SEQL * DMODEL * sizeof(u16);
    const bool zbf16 = (f_bytes + z_bytes) <= ws_size;
    void* zbuf = zbf16 ? (void*)((char*)d_ws + f_bytes) : (void*)y;

    if (zbf16) {
        hipLaunchKernelGGL((k_scan<true>), dim3(nb + BATCH * NSTATE), dim3(256), 0, stream,
                           u, A_log, C, Dv, delta, fal, rw, B, f, zbuf, st, nb);
    } else {
        hipLaunchKernelGGL((k_scan<false>), dim3(nb + BATCH * NSTATE), dim3(256), 0, stream,
                           u, A_log, C, Dv, delta, fal, rw, B, f, zbuf, st, nb);
    }
    hipLaunchKernelGGL(k_pass2w, dim3(BATCH * NSTATE * DMODEL / 256), dim3(256), 0, stream,
                       A_log, delta, C, fal, f);
    if (zbf16) {
        hipLaunchKernelGGL((k_corr_ln<true>), dim3(BATCH * (SEQL / TSUB)), dim3(256), 0, stream,
                           zbuf, f, A_log, delta, gamma, beta, y);
    } else {
        hipLaunchKernelGGL((k_corr_ln<false>), dim3(BATCH * (SEQL / TSUB)), dim3(256), 0, stream,
                           zbuf, f, A_log, delta, gamma, beta, y);
    }
}